// Round 1
// baseline (4072.036 us; speedup 1.0000x reference)
//
#include <hip/hip_runtime.h>

// Hebbian plasticity update, B=2048 independent 128x128 problems.
//   k = obs @ key_W^T + key_b                [B,S,K]
//   v = mod * (brim @ val_W^T + val_b)       [B,S,V]
//   corr = k^T @ v                           [B,K,V]
//   reg  = k @ k                             [B,K,V]  (S==K==V==128)
//   out  = done ? w + A_w*(1-w)*corr - B_w*w*reg : w
//
// R1: fp32 baseline. One block (512 thr) per batch; k,v LDS-resident.
// LDS 2*128*132*4 = 135168 B -> 1 block/CU (8 waves). Compute-bound fp32.

constexpr int D  = 128;
constexpr int LD = D + 4;   // 132: LD%32==4 -> all phase patterns <=2-way conflicts

__device__ __forceinline__ float dot8(const float4& x0, const float4& x1,
                                      const float* __restrict__ w, float a) {
    float4 w0 = *(const float4*)w;
    float4 w1 = *(const float4*)(w + 4);
    a = fmaf(x0.x, w0.x, a);
    a = fmaf(x0.y, w0.y, a);
    a = fmaf(x0.z, w0.z, a);
    a = fmaf(x0.w, w0.w, a);
    a = fmaf(x1.x, w1.x, a);
    a = fmaf(x1.y, w1.y, a);
    a = fmaf(x1.z, w1.z, a);
    a = fmaf(x1.w, w1.w, a);
    return a;
}

__global__ __launch_bounds__(512, 1)
void hebb_fp32(const float* __restrict__ obs,
               const float* __restrict__ brim,
               const float* __restrict__ modu,
               const float* __restrict__ was,
               const float* __restrict__ keyW,
               const float* __restrict__ keyB,
               const float* __restrict__ valW,
               const float* __restrict__ valB,
               const float* __restrict__ Aw,
               const float* __restrict__ Bw,
               const int* __restrict__ done,
               float* __restrict__ out)
{
    __shared__ float kS[D][LD];
    __shared__ float vS[D][LD];

    const int b = blockIdx.x;
    const int t = threadIdx.x;

    // ---------------- Phase 1: encoders k and v into LDS ----------------
    {
        const int row = t >> 2;          // 0..127  (4 threads per row)
        const int jb  = (t & 3) * 32;    // 0/32/64/96

        // ---- k row-segment ----
        const float* __restrict__ orow = obs + ((size_t)b * D + row) * D;
        float acc[32];
        #pragma unroll
        for (int j = 0; j < 32; ++j) acc[j] = keyB[jb + j];

        for (int c = 0; c < D; c += 8) {
            float4 x0 = *(const float4*)(orow + c);
            float4 x1 = *(const float4*)(orow + c + 4);
            #pragma unroll
            for (int j = 0; j < 32; ++j) {
                acc[j] = dot8(x0, x1, keyW + (size_t)(jb + j) * D + c, acc[j]);
            }
        }
        #pragma unroll
        for (int q = 0; q < 8; ++q)
            *(float4*)&kS[row][jb + 4 * q] =
                make_float4(acc[4*q], acc[4*q+1], acc[4*q+2], acc[4*q+3]);

        // ---- v row-segment (neuromodulated) ----
        const float* __restrict__ hrow = brim + ((size_t)b * D + row) * D;
        const float  mrow = modu[b * D + row];
        #pragma unroll
        for (int j = 0; j < 32; ++j) acc[j] = valB[jb + j];

        for (int c = 0; c < D; c += 8) {
            float4 x0 = *(const float4*)(hrow + c);
            float4 x1 = *(const float4*)(hrow + c + 4);
            #pragma unroll
            for (int j = 0; j < 32; ++j) {
                acc[j] = dot8(x0, x1, valW + (size_t)(jb + j) * D + c, acc[j]);
            }
        }
        #pragma unroll
        for (int q = 0; q < 8; ++q)
            *(float4*)&vS[row][jb + 4 * q] =
                make_float4(mrow*acc[4*q], mrow*acc[4*q+1],
                            mrow*acc[4*q+2], mrow*acc[4*q+3]);
    }

    __syncthreads();

    // ---------------- Phase 2: corr = k^T v, reg = k k ----------------
    // Thread owns rows {2rg, 2rg+1}, cols {4cb + 32q + e}. The strided col
    // pattern makes the 8 lanes' float4 reads cover all 32 banks exactly.
    const int rg = t >> 3;            // 0..63
    const int i0 = rg * 2;
    const int cb = (t & 7) * 4;       // 0,4,...,28

    float cc[2][16];   // corr accum
    float rr[2][16];   // reg accum
    #pragma unroll
    for (int r = 0; r < 2; ++r)
        #pragma unroll
        for (int j = 0; j < 16; ++j) { cc[r][j] = 0.0f; rr[r][j] = 0.0f; }

    for (int s = 0; s < D; ++s) {
        const float a0 = kS[s][i0];
        const float a1 = kS[s][i0 + 1];
        #pragma unroll
        for (int q = 0; q < 4; ++q) {
            float4 bv = *(const float4*)&vS[s][cb + 32 * q];
            cc[0][4*q+0] = fmaf(a0, bv.x, cc[0][4*q+0]);
            cc[0][4*q+1] = fmaf(a0, bv.y, cc[0][4*q+1]);
            cc[0][4*q+2] = fmaf(a0, bv.z, cc[0][4*q+2]);
            cc[0][4*q+3] = fmaf(a0, bv.w, cc[0][4*q+3]);
            cc[1][4*q+0] = fmaf(a1, bv.x, cc[1][4*q+0]);
            cc[1][4*q+1] = fmaf(a1, bv.y, cc[1][4*q+1]);
            cc[1][4*q+2] = fmaf(a1, bv.z, cc[1][4*q+2]);
            cc[1][4*q+3] = fmaf(a1, bv.w, cc[1][4*q+3]);
        }
    }

    for (int m = 0; m < D; ++m) {
        const float a0 = kS[i0][m];
        const float a1 = kS[i0 + 1][m];
        #pragma unroll
        for (int q = 0; q < 4; ++q) {
            float4 bv = *(const float4*)&kS[m][cb + 32 * q];
            rr[0][4*q+0] = fmaf(a0, bv.x, rr[0][4*q+0]);
            rr[0][4*q+1] = fmaf(a0, bv.y, rr[0][4*q+1]);
            rr[0][4*q+2] = fmaf(a0, bv.z, rr[0][4*q+2]);
            rr[0][4*q+3] = fmaf(a0, bv.w, rr[0][4*q+3]);
            rr[1][4*q+0] = fmaf(a1, bv.x, rr[1][4*q+0]);
            rr[1][4*q+1] = fmaf(a1, bv.y, rr[1][4*q+1]);
            rr[1][4*q+2] = fmaf(a1, bv.z, rr[1][4*q+2]);
            rr[1][4*q+3] = fmaf(a1, bv.w, rr[1][4*q+3]);
        }
    }

    // ---------------- Epilogue: fused elementwise combine ----------------
    const float dsc   = done[b] ? 1.0f : 0.0f;
    const size_t obase = (size_t)b * D * D;

    #pragma unroll
    for (int r = 0; r < 2; ++r) {
        const int i = i0 + r;
        #pragma unroll
        for (int q = 0; q < 4; ++q) {
            const int j = cb + 32 * q;
            float4 w  = *(const float4*)&was[obase + (size_t)i * D + j];
            float4 aw = *(const float4*)&Aw[i * D + j];
            float4 bw = *(const float4*)&Bw[i * D + j];
            float4 o;
            o.x = w.x + dsc * (aw.x * (1.0f - w.x) * cc[r][4*q+0] - bw.x * w.x * rr[r][4*q+0]);
            o.y = w.y + dsc * (aw.y * (1.0f - w.y) * cc[r][4*q+1] - bw.y * w.y * rr[r][4*q+1]);
            o.z = w.z + dsc * (aw.z * (1.0f - w.z) * cc[r][4*q+2] - bw.z * w.z * rr[r][4*q+2]);
            o.w = w.w + dsc * (aw.w * (1.0f - w.w) * cc[r][4*q+3] - bw.w * w.w * rr[r][4*q+3]);
            *(float4*)&out[obase + (size_t)i * D + j] = o;
        }
    }
}

extern "C" void kernel_launch(void* const* d_in, const int* in_sizes, int n_in,
                              void* d_out, int out_size, void* d_ws, size_t ws_size,
                              hipStream_t stream) {
    const float* obs  = (const float*)d_in[0];
    const float* brim = (const float*)d_in[1];
    const float* modu = (const float*)d_in[2];
    const float* was  = (const float*)d_in[3];
    const float* keyW = (const float*)d_in[4];
    const float* keyB = (const float*)d_in[5];
    const float* valW = (const float*)d_in[6];
    const float* valB = (const float*)d_in[7];
    const float* Aw   = (const float*)d_in[8];
    const float* Bw   = (const float*)d_in[9];
    const int*   done = (const int*)d_in[10];
    float* out = (float*)d_out;

    const int B = in_sizes[10];   // 2048 batches

    hipLaunchKernelGGL(hebb_fp32, dim3(B), dim3(512), 0, stream,
                       obs, brim, modu, was, keyW, keyB, valW, valB, Aw, Bw,
                       done, out);
}

// Round 2
// 494.868 us; speedup vs baseline: 8.2285x; 8.2285x over previous
//
#include <hip/hip_runtime.h>

// Hebbian plasticity update, B=2048 independent 128x128 problems — R2: MFMA.
//   k  = obs @ keyW^T + key_b            [S,K]
//   kT = keyW @ obs^T + key_b (rows=o)   [K,S]   (direct MFMA, avoids LDS transpose)
//   vT = mod ⊙ (valW @ brim^T + val_b)   [V,S]
//   corr[i][j] = sum_s kT[i][s]*vT[j][s]
//   reg [i][j] = sum_m k[i][m]*kT[j][m]
//   out = done ? w + A_w*(1-w)*corr - B_w*w*reg : w
// All fragments are "8 consecutive k from a row" for BOTH A and B -> result
// invariant to the intra-lane k-order (sum over k is permutation-invariant).

typedef __attribute__((ext_vector_type(8))) short bf16x8;
typedef __attribute__((ext_vector_type(4))) float f32x4;

constexpr int D   = 128;
constexpr int LDB = 136;   // bf16 row stride (+8 pad = +16B -> conflict-free b128 reads)

__device__ __forceinline__ short f2bf(float x) {   // RNE fp32->bf16
    unsigned u = __builtin_bit_cast(unsigned, x);
    u += 0x7fff + ((u >> 16) & 1);
    return (short)(u >> 16);
}

__global__ void cvt_weights(const float* __restrict__ kw,
                            const float* __restrict__ vw,
                            short* __restrict__ o) {
    int i = blockIdx.x * 256 + threadIdx.x;      // 16384 threads
    o[i]         = f2bf(kw[i]);
    o[16384 + i] = f2bf(vw[i]);
}

__global__ __launch_bounds__(512, 1)
void hebb_mfma(const float* __restrict__ obs,
               const float* __restrict__ brim,
               const float* __restrict__ modu,
               const float* __restrict__ was,
               const short* __restrict__ keyWb,
               const float* __restrict__ keyB,
               const short* __restrict__ valWb,
               const float* __restrict__ valB,
               const float* __restrict__ Aw,
               const float* __restrict__ Bw,
               const int* __restrict__ done,
               float* __restrict__ out)
{
    __shared__ __align__(16) short xS [D * LDB];   // staging: obs, then brim (bf16)
    __shared__ __align__(16) short kS [D * LDB];   // k  [s][o]
    __shared__ __align__(16) short kTS[D * LDB];   // kT [o][s]
    __shared__ __align__(16) short vTS[D * LDB];   // vT [o][s]

    const int b  = blockIdx.x;
    const int t  = threadIdx.x;
    const int w  = t >> 6;        // wave 0..7 -> owns rows [16w,16w+16)
    const int l  = t & 63;
    const int lr = l & 15;        // A-row / B-col lane index
    const int hg = l >> 4;        // k-group 0..3

    // ---------- 1a: stage obs -> xS ----------
    {
        const float4* src = (const float4*)(obs + (size_t)b * D * D);
        #pragma unroll
        for (int i = 0; i < 8; ++i) {
            float4 g = src[i * 512 + t];
            int f = (i * 512 + t) * 4;
            int row = f >> 7, col = f & 127;
            short4 s4 = make_short4(f2bf(g.x), f2bf(g.y), f2bf(g.z), f2bf(g.w));
            *(short4*)&xS[row * LDB + col] = s4;
        }
    }
    __syncthreads();

    // ---------- 1b: k strip (A=obs,B=keyW) and kT strip (A=keyW,B=obs) ----------
    f32x4 acc[8], acc2[8];
    #pragma unroll
    for (int i = 0; i < 8; ++i) { acc[i] = f32x4{0.f,0.f,0.f,0.f}; acc2[i] = f32x4{0.f,0.f,0.f,0.f}; }

    for (int c = 0; c < 4; ++c) {
        const int c0 = c * 32 + 8 * hg;
        bf16x8 aK = *(const bf16x8*)&xS[(16 * w + lr) * LDB + c0];
        bf16x8 aT = *(const bf16x8*)&keyWb[(16 * w + lr) * D + c0];
        #pragma unroll
        for (int q = 0; q < 8; ++q) {
            bf16x8 bK = *(const bf16x8*)&keyWb[(16 * q + lr) * D + c0];
            bf16x8 bT = *(const bf16x8*)&xS[(16 * q + lr) * LDB + c0];
            acc[q]  = __builtin_amdgcn_mfma_f32_16x16x32_bf16(aK, bK, acc[q],  0, 0, 0);
            acc2[q] = __builtin_amdgcn_mfma_f32_16x16x32_bf16(aT, bT, acc2[q], 0, 0, 0);
        }
    }
    {
        float kbR[4];
        #pragma unroll
        for (int r = 0; r < 4; ++r) kbR[r] = keyB[16 * w + 4 * hg + r];
        #pragma unroll
        for (int q = 0; q < 8; ++q) {
            float kbC = keyB[16 * q + lr];
            #pragma unroll
            for (int r = 0; r < 4; ++r) {
                kS [(16 * w + 4 * hg + r) * LDB + 16 * q + lr] = f2bf(acc[q][r]  + kbC);
                kTS[(16 * w + 4 * hg + r) * LDB + 16 * q + lr] = f2bf(acc2[q][r] + kbR[r]);
            }
        }
    }
    __syncthreads();

    // ---------- 1c: stage brim -> xS ----------
    {
        const float4* src = (const float4*)(brim + (size_t)b * D * D);
        #pragma unroll
        for (int i = 0; i < 8; ++i) {
            float4 g = src[i * 512 + t];
            int f = (i * 512 + t) * 4;
            int row = f >> 7, col = f & 127;
            short4 s4 = make_short4(f2bf(g.x), f2bf(g.y), f2bf(g.z), f2bf(g.w));
            *(short4*)&xS[row * LDB + col] = s4;
        }
    }
    __syncthreads();

    // ---------- 1d: vT strip (A=valW, B=brim), scaled by modulation ----------
    #pragma unroll
    for (int i = 0; i < 8; ++i) acc[i] = f32x4{0.f,0.f,0.f,0.f};
    for (int c = 0; c < 4; ++c) {
        const int c0 = c * 32 + 8 * hg;
        bf16x8 aV = *(const bf16x8*)&valWb[(16 * w + lr) * D + c0];
        #pragma unroll
        for (int q = 0; q < 8; ++q) {
            bf16x8 bV = *(const bf16x8*)&xS[(16 * q + lr) * LDB + c0];
            acc[q] = __builtin_amdgcn_mfma_f32_16x16x32_bf16(aV, bV, acc[q], 0, 0, 0);
        }
    }
    {
        float vbR[4];
        #pragma unroll
        for (int r = 0; r < 4; ++r) vbR[r] = valB[16 * w + 4 * hg + r];
        #pragma unroll
        for (int q = 0; q < 8; ++q) {
            float m = modu[(size_t)b * D + 16 * q + lr];
            #pragma unroll
            for (int r = 0; r < 4; ++r)
                vTS[(16 * w + 4 * hg + r) * LDB + 16 * q + lr] = f2bf(m * (acc[q][r] + vbR[r]));
        }
    }
    __syncthreads();

    // ---------- 2: corr (A=kT,B=vT-rows) and reg (A=k,B=kT-rows) ----------
    f32x4 cacc[8], racc[8];
    #pragma unroll
    for (int i = 0; i < 8; ++i) { cacc[i] = f32x4{0.f,0.f,0.f,0.f}; racc[i] = f32x4{0.f,0.f,0.f,0.f}; }

    for (int c = 0; c < 4; ++c) {
        const int c0 = c * 32 + 8 * hg;
        bf16x8 aC = *(const bf16x8*)&kTS[(16 * w + lr) * LDB + c0];
        bf16x8 aR = *(const bf16x8*)&kS [(16 * w + lr) * LDB + c0];
        #pragma unroll
        for (int q = 0; q < 8; ++q) {
            bf16x8 bC = *(const bf16x8*)&vTS[(16 * q + lr) * LDB + c0];
            bf16x8 bR = *(const bf16x8*)&kTS[(16 * q + lr) * LDB + c0];
            cacc[q] = __builtin_amdgcn_mfma_f32_16x16x32_bf16(aC, bC, cacc[q], 0, 0, 0);
            racc[q] = __builtin_amdgcn_mfma_f32_16x16x32_bf16(aR, bR, racc[q], 0, 0, 0);
        }
    }

    // ---------- epilogue: fused elementwise combine ----------
    const float dsc = done[b] ? 1.0f : 0.0f;
    const size_t ob = (size_t)b * D * D;
    #pragma unroll
    for (int q = 0; q < 8; ++q) {
        const int j = 16 * q + lr;
        #pragma unroll
        for (int r = 0; r < 4; ++r) {
            const int i  = 16 * w + 4 * hg + r;
            const int ij = i * D + j;
            float wv = was[ob + ij];
            out[ob + ij] = wv + dsc * (Aw[ij] * (1.0f - wv) * cacc[q][r]
                                     - Bw[ij] * wv * racc[q][r]);
        }
    }
}

extern "C" void kernel_launch(void* const* d_in, const int* in_sizes, int n_in,
                              void* d_out, int out_size, void* d_ws, size_t ws_size,
                              hipStream_t stream) {
    const float* obs  = (const float*)d_in[0];
    const float* brim = (const float*)d_in[1];
    const float* modu = (const float*)d_in[2];
    const float* was  = (const float*)d_in[3];
    const float* keyW = (const float*)d_in[4];
    const float* keyB = (const float*)d_in[5];
    const float* valW = (const float*)d_in[6];
    const float* valB = (const float*)d_in[7];
    const float* Aw   = (const float*)d_in[8];
    const float* Bw   = (const float*)d_in[9];
    const int*   done = (const int*)d_in[10];
    float* out = (float*)d_out;

    const int B = in_sizes[10];                 // 2048 batches
    short* wb = (short*)d_ws;                   // [0,32K): keyW bf16, [32K,64K): valW bf16

    hipLaunchKernelGGL(cvt_weights, dim3(64), dim3(256), 0, stream, keyW, valW, wb);
    hipLaunchKernelGGL(hebb_mfma, dim3(B), dim3(512), 0, stream,
                       obs, brim, modu, was, wb, keyB, wb + 16384, valB,
                       Aw, Bw, done, out);
}